// Round 1
// baseline (1079.057 us; speedup 1.0000x reference)
//
#include <hip/hip_runtime.h>
#include <cmath>

// Problem constants
#define B_SZ   32
#define LQ     576
#define LV     3024
#define CDIM   384
#define NHEAD  6
#define DHEAD  64
#define NLVL   3
#define NPTS   4

// ---------------------------------------------------------------------------
// Generic fp32 GEMM: C[M,N] = A[M,K] @ B[K,N] + bias[N]
// 64x64 tile, 256 threads, 4x4 per thread. REQUIRES: M % 64 == 0, K % 16 == 0,
// N % 4 == 0. (All call sites satisfy this: M in {96768, 18432}, K = 384,
// N in {384, 144, 72}.)
// ---------------------------------------------------------------------------
__global__ __launch_bounds__(256) void gemm_bias_kernel(
    const float* __restrict__ A, const float* __restrict__ B,
    const float* __restrict__ bias, float* __restrict__ C,
    int M, int N, int K)
{
    const int BK = 16;
    __shared__ float As[BK][64 + 1];
    __shared__ float Bs[BK][64 + 1];

    const int tid = threadIdx.x;
    const int tx = tid & 15;   // col group (4 cols each)
    const int ty = tid >> 4;   // row group (4 rows each)
    const int m0 = blockIdx.y * 64;
    const int n0 = blockIdx.x * 64;

    // A-load: row = tid/4 (0..63), kk = (tid%4)*4  -> float4 along K
    const int a_row = tid >> 2;
    const int a_kk  = (tid & 3) << 2;
    // B-load: kr = tid/16 (0..15), nn = (tid%16)*4 -> float4 along N
    const int b_kr = tid >> 4;
    const int b_nn = (tid & 15) << 2;

    float acc[4][4] = {};

    for (int k0 = 0; k0 < K; k0 += BK) {
        const float4 av = *(const float4*)(A + (size_t)(m0 + a_row) * K + k0 + a_kk);
        As[a_kk + 0][a_row] = av.x;
        As[a_kk + 1][a_row] = av.y;
        As[a_kk + 2][a_row] = av.z;
        As[a_kk + 3][a_row] = av.w;

        float4 bv = make_float4(0.f, 0.f, 0.f, 0.f);
        if (n0 + b_nn < N)  // N % 4 == 0 -> float4 fully in or out
            bv = *(const float4*)(B + (size_t)(k0 + b_kr) * N + n0 + b_nn);
        Bs[b_kr][b_nn + 0] = bv.x;
        Bs[b_kr][b_nn + 1] = bv.y;
        Bs[b_kr][b_nn + 2] = bv.z;
        Bs[b_kr][b_nn + 3] = bv.w;
        __syncthreads();

        #pragma unroll
        for (int kk = 0; kk < BK; ++kk) {
            float a[4], b[4];
            #pragma unroll
            for (int i = 0; i < 4; ++i) a[i] = As[kk][ty * 4 + i];
            #pragma unroll
            for (int j = 0; j < 4; ++j) b[j] = Bs[kk][tx * 4 + j];
            #pragma unroll
            for (int i = 0; i < 4; ++i)
                #pragma unroll
                for (int j = 0; j < 4; ++j)
                    acc[i][j] += a[i] * b[j];
        }
        __syncthreads();
    }

    #pragma unroll
    for (int i = 0; i < 4; ++i) {
        const int m = m0 + ty * 4 + i;
        #pragma unroll
        for (int j = 0; j < 4; ++j) {
            const int n = n0 + tx * 4 + j;
            if (n < N)
                C[(size_t)m * N + n] = acc[i][j] + bias[n];
        }
    }
}

// ---------------------------------------------------------------------------
// Reference-point processing: rp (B, 3024, 2) -> refp (B, 576, 2)
// p1 = mean over first 2304 pts; p2 = pts 2304..2879; p3 = bilinear 12x12->24x24
// (jax.image.resize half-pixel: src = 0.5*i - 0.25, edge-renormalized ==
//  clamp coordinate to [0,11] then bilinear with clamped indices)
// ---------------------------------------------------------------------------
__global__ __launch_bounds__(256) void ref_kernel(
    const float* __restrict__ rp, float* __restrict__ refp)
{
    const int b = blockIdx.x;
    const float* r = rp + (size_t)b * LV * 2;
    const int tid = threadIdx.x;

    __shared__ float redx[256], redy[256];
    float sx = 0.f, sy = 0.f;
    for (int i = tid; i < 2304; i += 256) {
        sx += r[2 * i + 0];
        sy += r[2 * i + 1];
    }
    redx[tid] = sx; redy[tid] = sy;
    __syncthreads();
    for (int s = 128; s > 0; s >>= 1) {
        if (tid < s) { redx[tid] += redx[tid + s]; redy[tid] += redy[tid + s]; }
        __syncthreads();
    }
    const float p1x = redx[0] * (1.f / 2304.f);
    const float p1y = redy[0] * (1.f / 2304.f);

    const float* g = r + 2880 * 2;  // 12x12 level
    for (int q = tid; q < 576; q += 256) {
        const float p2x = r[(2304 + q) * 2 + 0];
        const float p2y = r[(2304 + q) * 2 + 1];
        const int qy = q / 24, qx = q % 24;
        const float syc = fminf(fmaxf(0.5f * qy - 0.25f, 0.f), 11.f);
        const float sxc = fminf(fmaxf(0.5f * qx - 0.25f, 0.f), 11.f);
        int y0 = min((int)syc, 10);  // floor (non-negative) clamped so y0+1<=11
        int x0 = min((int)sxc, 10);
        const float fy = syc - (float)y0, fx = sxc - (float)x0;
        const float v00x = g[(y0 * 12 + x0) * 2 + 0],     v00y = g[(y0 * 12 + x0) * 2 + 1];
        const float v10x = g[(y0 * 12 + x0 + 1) * 2 + 0], v10y = g[(y0 * 12 + x0 + 1) * 2 + 1];
        const float v01x = g[((y0 + 1) * 12 + x0) * 2 + 0],     v01y = g[((y0 + 1) * 12 + x0) * 2 + 1];
        const float v11x = g[((y0 + 1) * 12 + x0 + 1) * 2 + 0], v11y = g[((y0 + 1) * 12 + x0 + 1) * 2 + 1];
        const float p3x = (1.f - fy) * ((1.f - fx) * v00x + fx * v10x)
                        + fy * ((1.f - fx) * v01x + fx * v11x);
        const float p3y = (1.f - fy) * ((1.f - fx) * v00y + fx * v10y)
                        + fy * ((1.f - fx) * v01y + fx * v11y);
        refp[((size_t)b * LQ + q) * 2 + 0] = (p1x + p2x + p3x) * (1.f / 3.f);
        refp[((size_t)b * LQ + q) * 2 + 1] = (p1y + p2y + p3y) * (1.f / 3.f);
    }
}

// ---------------------------------------------------------------------------
// Deformable sampling + softmax + attention-weighted accumulation.
// One block per (b, q). 384 threads = 6 heads x 64 channels.
//   val    (B, 3024, 384)   off (B*576, 144)   logits (B*576, 72)
//   refp   (B*576, 2)       mid (B*576, 384)
// ---------------------------------------------------------------------------
__global__ __launch_bounds__(384) void sample_kernel(
    const float* __restrict__ val, const float* __restrict__ off,
    const float* __restrict__ logits, const float* __restrict__ refp,
    float* __restrict__ mid)
{
    const int bq = blockIdx.x;
    const int b = bq / LQ;
    const int tid = threadIdx.x;

    __shared__ float attn[72];
    __shared__ int   sloc[72][4];
    __shared__ float swt[72][4];

    if (tid < 72) {
        attn[tid] = logits[(size_t)bq * 72 + tid];

        const int h = tid / 12;
        const int r = tid % 12;
        const int l = r >> 2;
        const int p = r & 3;

        const int HL[3] = {48, 24, 12};
        const int ST[3] = {0, 2304, 2880};
        const int Hl = HL[l], Wl = HL[l], st = ST[l];

        const float rx = refp[bq * 2 + 0];
        const float ry = refp[bq * 2 + 1];
        const int oc = ((h * NLVL + l) * NPTS + p) * 2;
        const float cx = off[(size_t)bq * 144 + oc + 0] + rx;
        const float cy = off[(size_t)bq * 144 + oc + 1] + ry;

        const float px = cx * (float)Wl - 0.5f;
        const float py = cy * (float)Hl - 0.5f;
        const float x0f = floorf(px), y0f = floorf(py);
        const float lx = px - x0f, ly = py - y0f;
        const int x0 = (int)x0f, y0 = (int)y0f;

        #pragma unroll
        for (int k = 0; k < 4; ++k) {
            const int dx = k & 1, dy = k >> 1;
            const int xi = x0 + dx, yi = y0 + dy;
            const bool v = (xi >= 0) && (xi < Wl) && (yi >= 0) && (yi < Hl);
            const int xc = min(max(xi, 0), Wl - 1);
            const int yc = min(max(yi, 0), Hl - 1);
            sloc[tid][k] = st + yc * Wl + xc;
            const float wx = dx ? lx : 1.f - lx;
            const float wy = dy ? ly : 1.f - ly;
            swt[tid][k] = v ? wx * wy : 0.f;
        }
    }
    __syncthreads();

    if (tid < NHEAD) {  // softmax over the 12 (l,p) logits of head `tid`
        float mx = -1e30f;
        #pragma unroll
        for (int j = 0; j < 12; ++j) mx = fmaxf(mx, attn[tid * 12 + j]);
        float s = 0.f;
        #pragma unroll
        for (int j = 0; j < 12; ++j) {
            const float e = expf(attn[tid * 12 + j] - mx);
            attn[tid * 12 + j] = e;
            s += e;
        }
        const float inv = 1.f / s;
        #pragma unroll
        for (int j = 0; j < 12; ++j) attn[tid * 12 + j] *= inv;
    }
    __syncthreads();

    const int h = tid >> 6;   // head
    const int c = tid & 63;   // channel
    const float* vb = val + (size_t)b * LV * CDIM + h * DHEAD + c;
    float acc = 0.f;
    #pragma unroll
    for (int s = 0; s < 12; ++s) {
        const int j = h * 12 + s;
        const float a = attn[j];
        const float sum = swt[j][0] * vb[(size_t)sloc[j][0] * CDIM]
                        + swt[j][1] * vb[(size_t)sloc[j][1] * CDIM]
                        + swt[j][2] * vb[(size_t)sloc[j][2] * CDIM]
                        + swt[j][3] * vb[(size_t)sloc[j][3] * CDIM];
        acc += a * sum;
    }
    mid[(size_t)bq * CDIM + tid] = acc;
}

// ---------------------------------------------------------------------------
extern "C" void kernel_launch(void* const* d_in, const int* in_sizes, int n_in,
                              void* d_out, int out_size, void* d_ws, size_t ws_size,
                              hipStream_t stream)
{
    (void)in_sizes; (void)n_in; (void)out_size; (void)ws_size;

    const float* query   = (const float*)d_in[0];   // (32, 576, 384)
    const float* value   = (const float*)d_in[1];   // (32, 3024, 384)
    const float* rp      = (const float*)d_in[2];   // (32, 3024, 1, 2)
    const float* W_value = (const float*)d_in[3];
    const float* b_value = (const float*)d_in[4];
    const float* W_off   = (const float*)d_in[5];
    const float* b_off   = (const float*)d_in[6];
    const float* W_attn  = (const float*)d_in[7];
    const float* b_attn  = (const float*)d_in[8];
    const float* W_out   = (const float*)d_in[9];
    const float* b_out   = (const float*)d_in[10];
    float* out = (float*)d_out;

    // Workspace layout (fp32): val | off | logits | refp | mid  (~193 MB)
    float* ws     = (float*)d_ws;
    float* val    = ws;                                    // 32*3024*384
    float* offb   = val  + (size_t)B_SZ * LV * CDIM;       // 18432*144
    float* logit  = offb + (size_t)B_SZ * LQ * 144;        // 18432*72
    float* refp   = logit + (size_t)B_SZ * LQ * 72;        // 18432*2
    float* mid    = refp + (size_t)B_SZ * LQ * 2;          // 18432*384

    const int Mv = B_SZ * LV;   // 96768
    const int Mq = B_SZ * LQ;   // 18432

    // 1) val = value @ W_value + b_value
    gemm_bias_kernel<<<dim3(CDIM / 64, Mv / 64), 256, 0, stream>>>(
        value, W_value, b_value, val, Mv, CDIM, CDIM);
    // 2) off = query @ W_off + b_off   (N = 144)
    gemm_bias_kernel<<<dim3((144 + 63) / 64, Mq / 64), 256, 0, stream>>>(
        query, W_off, b_off, offb, Mq, 144, CDIM);
    // 3) logits = query @ W_attn + b_attn   (N = 72)
    gemm_bias_kernel<<<dim3((72 + 63) / 64, Mq / 64), 256, 0, stream>>>(
        query, W_attn, b_attn, logit, Mq, 72, CDIM);
    // 4) reference points
    ref_kernel<<<B_SZ, 256, 0, stream>>>(rp, refp);
    // 5) softmax + deformable sampling + attention accumulate
    sample_kernel<<<Mq, 384, 0, stream>>>(val, offb, logit, refp, mid);
    // 6) out = mid @ W_out + b_out
    gemm_bias_kernel<<<dim3(CDIM / 64, Mq / 64), 256, 0, stream>>>(
        mid, W_out, b_out, out, Mq, CDIM, CDIM);
}

// Round 2
// 558.200 us; speedup vs baseline: 1.9331x; 1.9331x over previous
//
#include <hip/hip_runtime.h>
#include <cmath>

// Problem constants
#define B_SZ   32
#define LQ     576
#define LV     3024
#define CDIM   384
#define NHEAD  6
#define DHEAD  64
#define NLVL   3
#define NPTS   4

typedef short  bx4 __attribute__((ext_vector_type(4)));   // 4 bf16 (8 B)
typedef short  bx8 __attribute__((ext_vector_type(8)));   // 8 bf16 (16 B, MFMA A/B frag)
typedef float  fx4 __attribute__((ext_vector_type(4)));   // MFMA C/D frag

__device__ __forceinline__ short f2bf(float f) {
    unsigned u = __builtin_bit_cast(unsigned, f);
    unsigned r = (u + 0x7FFFu + ((u >> 16) & 1u)) >> 16;  // RNE
    return (short)r;
}

// ---------------------------------------------------------------------------
// W (K x N fp32, row-major) -> Wt (N x K bf16)  [tiny: 384x384]
// ---------------------------------------------------------------------------
__global__ __launch_bounds__(256) void cast_transpose_kernel(
    const float* __restrict__ W, short* __restrict__ Wt, int K, int N)
{
    int idx = blockIdx.x * 256 + threadIdx.x;
    if (idx >= K * N) return;
    int n = idx / K, k = idx - n * K;
    Wt[idx] = f2bf(W[(size_t)k * N + n]);
}

// ---------------------------------------------------------------------------
// bf16 MFMA GEMM: C[M,N] = A[M,K](fp32, cast in-flight) @ Wt[N,K](bf16)^T + bias
// 128x128 tile, BK=64, 256 threads (4 waves), each wave 64x64 via 4x4 grid of
// 16x16x32 MFMA. REQUIRES M%128==0, N%128==0, K%64==0. (M in {96768,18432},
// N=384, K=384.)  LDS rows padded to 72 shorts -> frag reads <=2-way banked.
// ---------------------------------------------------------------------------
__global__ __launch_bounds__(256) void gemm_mfma_kernel(
    const float* __restrict__ A, const short* __restrict__ Wt,
    const float* __restrict__ bias, float* __restrict__ C,
    int M, int N, int K)
{
    __shared__ short As[128 * 72];
    __shared__ short Bs[128 * 72];

    const int tid = threadIdx.x;
    const int m0 = blockIdx.y * 128;
    const int n0 = blockIdx.x * 128;

    // A-stage indexing: 16 threads cover 64 k as float4; 16 rows per pass, 8 passes
    const int akq = (tid & 15) << 2;   // k offset (floats)
    const int am  = tid >> 4;          // row 0..15
    // B-stage indexing: 8 threads cover 64 k as short8; 32 rows per pass, 4 passes
    const int bk8 = (tid & 7) << 3;    // k offset (shorts)
    const int bn  = tid >> 3;          // row 0..31

    const int w  = tid >> 6;           // wave 0..3
    const int l  = tid & 63;
    const int mw = (w & 1) * 64;
    const int nw = (w >> 1) * 64;
    const int lr = l & 15;
    const int ko = (l >> 4) * 8;       // k offset within 32 (shorts)

    fx4 acc[4][4] = {};

    for (int k0 = 0; k0 < K; k0 += 64) {
        // ---- stage A (fp32 -> bf16) ----
        #pragma unroll
        for (int r = 0; r < 8; ++r) {
            const int m = am + r * 16;
            const float4 v = *(const float4*)(A + (size_t)(m0 + m) * K + k0 + akq);
            bx4 s;
            s[0] = f2bf(v.x); s[1] = f2bf(v.y); s[2] = f2bf(v.z); s[3] = f2bf(v.w);
            *(bx4*)&As[m * 72 + akq] = s;
        }
        // ---- stage B (bf16 passthrough from Wt[n][k]) ----
        #pragma unroll
        for (int r = 0; r < 4; ++r) {
            const int n = bn + r * 32;
            const bx8 wv = *(const bx8*)(Wt + (size_t)(n0 + n) * K + k0 + bk8);
            *(bx8*)&Bs[n * 72 + bk8] = wv;
        }
        __syncthreads();

        // ---- MFMA: 2 k-steps of 32 ----
        #pragma unroll
        for (int ks = 0; ks < 2; ++ks) {
            bx8 af[4], bf[4];
            #pragma unroll
            for (int i = 0; i < 4; ++i)
                af[i] = *(const bx8*)&As[(mw + i * 16 + lr) * 72 + ks * 32 + ko];
            #pragma unroll
            for (int j = 0; j < 4; ++j)
                bf[j] = *(const bx8*)&Bs[(nw + j * 16 + lr) * 72 + ks * 32 + ko];
            #pragma unroll
            for (int i = 0; i < 4; ++i)
                #pragma unroll
                for (int j = 0; j < 4; ++j)
                    acc[i][j] = __builtin_amdgcn_mfma_f32_16x16x32_bf16(
                        af[i], bf[j], acc[i][j], 0, 0, 0);
        }
        __syncthreads();
    }

    // ---- epilogue: C/D layout col=lane&15, row=(lane>>4)*4+reg ----
    const int rrow = (l >> 4) * 4;
    #pragma unroll
    for (int j = 0; j < 4; ++j) {
        const int col = n0 + nw + j * 16 + lr;
        const float bv = bias[col];
        #pragma unroll
        for (int i = 0; i < 4; ++i) {
            const int row = m0 + mw + i * 16 + rrow;
            #pragma unroll
            for (int r = 0; r < 4; ++r)
                C[(size_t)(row + r) * N + col] = acc[i][j][r] + bv;
        }
    }
}

// ---------------------------------------------------------------------------
// fp32 fallback GEMM for the small N (off: 144, logits: 72) projections.
// ---------------------------------------------------------------------------
__global__ __launch_bounds__(256) void gemm_bias_kernel(
    const float* __restrict__ A, const float* __restrict__ B,
    const float* __restrict__ bias, float* __restrict__ C,
    int M, int N, int K)
{
    const int BK = 16;
    __shared__ float Asm[BK][64 + 1];
    __shared__ float Bsm[BK][64 + 1];

    const int tid = threadIdx.x;
    const int tx = tid & 15;
    const int ty = tid >> 4;
    const int m0 = blockIdx.y * 64;
    const int n0 = blockIdx.x * 64;

    const int a_row = tid >> 2;
    const int a_kk  = (tid & 3) << 2;
    const int b_kr = tid >> 4;
    const int b_nn = (tid & 15) << 2;

    float acc[4][4] = {};

    for (int k0 = 0; k0 < K; k0 += BK) {
        const float4 av = *(const float4*)(A + (size_t)(m0 + a_row) * K + k0 + a_kk);
        Asm[a_kk + 0][a_row] = av.x;
        Asm[a_kk + 1][a_row] = av.y;
        Asm[a_kk + 2][a_row] = av.z;
        Asm[a_kk + 3][a_row] = av.w;

        float4 bv = make_float4(0.f, 0.f, 0.f, 0.f);
        if (n0 + b_nn < N)
            bv = *(const float4*)(B + (size_t)(k0 + b_kr) * N + n0 + b_nn);
        Bsm[b_kr][b_nn + 0] = bv.x;
        Bsm[b_kr][b_nn + 1] = bv.y;
        Bsm[b_kr][b_nn + 2] = bv.z;
        Bsm[b_kr][b_nn + 3] = bv.w;
        __syncthreads();

        #pragma unroll
        for (int kk = 0; kk < BK; ++kk) {
            float a[4], b[4];
            #pragma unroll
            for (int i = 0; i < 4; ++i) a[i] = Asm[kk][ty * 4 + i];
            #pragma unroll
            for (int j = 0; j < 4; ++j) b[j] = Bsm[kk][tx * 4 + j];
            #pragma unroll
            for (int i = 0; i < 4; ++i)
                #pragma unroll
                for (int j = 0; j < 4; ++j)
                    acc[i][j] += a[i] * b[j];
        }
        __syncthreads();
    }

    #pragma unroll
    for (int i = 0; i < 4; ++i) {
        const int m = m0 + ty * 4 + i;
        #pragma unroll
        for (int j = 0; j < 4; ++j) {
            const int n = n0 + tx * 4 + j;
            if (n < N)
                C[(size_t)m * N + n] = acc[i][j] + bias[n];
        }
    }
}

// ---------------------------------------------------------------------------
// Reference-point processing (unchanged, verified round 1)
// ---------------------------------------------------------------------------
__global__ __launch_bounds__(256) void ref_kernel(
    const float* __restrict__ rp, float* __restrict__ refp)
{
    const int b = blockIdx.x;
    const float* r = rp + (size_t)b * LV * 2;
    const int tid = threadIdx.x;

    __shared__ float redx[256], redy[256];
    float sx = 0.f, sy = 0.f;
    for (int i = tid; i < 2304; i += 256) {
        sx += r[2 * i + 0];
        sy += r[2 * i + 1];
    }
    redx[tid] = sx; redy[tid] = sy;
    __syncthreads();
    for (int s = 128; s > 0; s >>= 1) {
        if (tid < s) { redx[tid] += redx[tid + s]; redy[tid] += redy[tid + s]; }
        __syncthreads();
    }
    const float p1x = redx[0] * (1.f / 2304.f);
    const float p1y = redy[0] * (1.f / 2304.f);

    const float* g = r + 2880 * 2;
    for (int q = tid; q < 576; q += 256) {
        const float p2x = r[(2304 + q) * 2 + 0];
        const float p2y = r[(2304 + q) * 2 + 1];
        const int qy = q / 24, qx = q % 24;
        const float syc = fminf(fmaxf(0.5f * qy - 0.25f, 0.f), 11.f);
        const float sxc = fminf(fmaxf(0.5f * qx - 0.25f, 0.f), 11.f);
        int y0 = min((int)syc, 10);
        int x0 = min((int)sxc, 10);
        const float fy = syc - (float)y0, fx = sxc - (float)x0;
        const float v00x = g[(y0 * 12 + x0) * 2 + 0],     v00y = g[(y0 * 12 + x0) * 2 + 1];
        const float v10x = g[(y0 * 12 + x0 + 1) * 2 + 0], v10y = g[(y0 * 12 + x0 + 1) * 2 + 1];
        const float v01x = g[((y0 + 1) * 12 + x0) * 2 + 0],     v01y = g[((y0 + 1) * 12 + x0) * 2 + 1];
        const float v11x = g[((y0 + 1) * 12 + x0 + 1) * 2 + 0], v11y = g[((y0 + 1) * 12 + x0 + 1) * 2 + 1];
        const float p3x = (1.f - fy) * ((1.f - fx) * v00x + fx * v10x)
                        + fy * ((1.f - fx) * v01x + fx * v11x);
        const float p3y = (1.f - fy) * ((1.f - fx) * v00y + fx * v10y)
                        + fy * ((1.f - fx) * v01y + fx * v11y);
        refp[((size_t)b * LQ + q) * 2 + 0] = (p1x + p2x + p3x) * (1.f / 3.f);
        refp[((size_t)b * LQ + q) * 2 + 1] = (p1y + p2y + p3y) * (1.f / 3.f);
    }
}

// ---------------------------------------------------------------------------
// Deformable sampling + softmax + attention accumulate (unchanged)
// ---------------------------------------------------------------------------
__global__ __launch_bounds__(384) void sample_kernel(
    const float* __restrict__ val, const float* __restrict__ off,
    const float* __restrict__ logits, const float* __restrict__ refp,
    float* __restrict__ mid)
{
    const int bq = blockIdx.x;
    const int b = bq / LQ;
    const int tid = threadIdx.x;

    __shared__ float attn[72];
    __shared__ int   sloc[72][4];
    __shared__ float swt[72][4];

    if (tid < 72) {
        attn[tid] = logits[(size_t)bq * 72 + tid];

        const int h = tid / 12;
        const int r = tid % 12;
        const int l = r >> 2;
        const int p = r & 3;

        const int HL[3] = {48, 24, 12};
        const int ST[3] = {0, 2304, 2880};
        const int Hl = HL[l], Wl = HL[l], st = ST[l];

        const float rx = refp[bq * 2 + 0];
        const float ry = refp[bq * 2 + 1];
        const int oc = ((h * NLVL + l) * NPTS + p) * 2;
        const float cx = off[(size_t)bq * 144 + oc + 0] + rx;
        const float cy = off[(size_t)bq * 144 + oc + 1] + ry;

        const float px = cx * (float)Wl - 0.5f;
        const float py = cy * (float)Hl - 0.5f;
        const float x0f = floorf(px), y0f = floorf(py);
        const float lx = px - x0f, ly = py - y0f;
        const int x0 = (int)x0f, y0 = (int)y0f;

        #pragma unroll
        for (int k = 0; k < 4; ++k) {
            const int dx = k & 1, dy = k >> 1;
            const int xi = x0 + dx, yi = y0 + dy;
            const bool v = (xi >= 0) && (xi < Wl) && (yi >= 0) && (yi < Hl);
            const int xc = min(max(xi, 0), Wl - 1);
            const int yc = min(max(yi, 0), Hl - 1);
            sloc[tid][k] = st + yc * Wl + xc;
            const float wx = dx ? lx : 1.f - lx;
            const float wy = dy ? ly : 1.f - ly;
            swt[tid][k] = v ? wx * wy : 0.f;
        }
    }
    __syncthreads();

    if (tid < NHEAD) {
        float mx = -1e30f;
        #pragma unroll
        for (int j = 0; j < 12; ++j) mx = fmaxf(mx, attn[tid * 12 + j]);
        float s = 0.f;
        #pragma unroll
        for (int j = 0; j < 12; ++j) {
            const float e = expf(attn[tid * 12 + j] - mx);
            attn[tid * 12 + j] = e;
            s += e;
        }
        const float inv = 1.f / s;
        #pragma unroll
        for (int j = 0; j < 12; ++j) attn[tid * 12 + j] *= inv;
    }
    __syncthreads();

    const int h = tid >> 6;
    const int c = tid & 63;
    const float* vb = val + (size_t)b * LV * CDIM + h * DHEAD + c;
    float acc = 0.f;
    #pragma unroll
    for (int s = 0; s < 12; ++s) {
        const int j = h * 12 + s;
        const float a = attn[j];
        const float sum = swt[j][0] * vb[(size_t)sloc[j][0] * CDIM]
                        + swt[j][1] * vb[(size_t)sloc[j][1] * CDIM]
                        + swt[j][2] * vb[(size_t)sloc[j][2] * CDIM]
                        + swt[j][3] * vb[(size_t)sloc[j][3] * CDIM];
        acc += a * sum;
    }
    mid[(size_t)bq * CDIM + tid] = acc;
}

// ---------------------------------------------------------------------------
extern "C" void kernel_launch(void* const* d_in, const int* in_sizes, int n_in,
                              void* d_out, int out_size, void* d_ws, size_t ws_size,
                              hipStream_t stream)
{
    (void)in_sizes; (void)n_in; (void)out_size; (void)ws_size;

    const float* query   = (const float*)d_in[0];
    const float* value   = (const float*)d_in[1];
    const float* rp      = (const float*)d_in[2];
    const float* W_value = (const float*)d_in[3];
    const float* b_value = (const float*)d_in[4];
    const float* W_off   = (const float*)d_in[5];
    const float* b_off   = (const float*)d_in[6];
    const float* W_attn  = (const float*)d_in[7];
    const float* b_attn  = (const float*)d_in[8];
    const float* W_out   = (const float*)d_in[9];
    const float* b_out   = (const float*)d_in[10];
    float* out = (float*)d_out;

    // Workspace layout (fp32): val | off | logits | refp | mid | Wt(bf16)
    float* ws    = (float*)d_ws;
    float* val   = ws;                                    // 32*3024*384
    float* offb  = val   + (size_t)B_SZ * LV * CDIM;
    float* logit = offb  + (size_t)B_SZ * LQ * 144;
    float* refp  = logit + (size_t)B_SZ * LQ * 72;
    float* mid   = refp  + (size_t)B_SZ * LQ * 2;
    short* Wt    = (short*)(mid + (size_t)B_SZ * LQ * CDIM);  // 384*384 bf16

    const int Mv = B_SZ * LV;   // 96768
    const int Mq = B_SZ * LQ;   // 18432

    // 1) Wt = bf16(W_value^T); val = value @ W_value + b_value  (MFMA)
    cast_transpose_kernel<<<(CDIM * CDIM + 255) / 256, 256, 0, stream>>>(
        W_value, Wt, CDIM, CDIM);
    gemm_mfma_kernel<<<dim3(CDIM / 128, Mv / 128), 256, 0, stream>>>(
        value, Wt, b_value, val, Mv, CDIM, CDIM);
    // 2) off = query @ W_off + b_off  (fp32 — coordinate-sensitive path)
    gemm_bias_kernel<<<dim3((144 + 63) / 64, Mq / 64), 256, 0, stream>>>(
        query, W_off, b_off, offb, Mq, 144, CDIM);
    // 3) logits = query @ W_attn + b_attn  (fp32)
    gemm_bias_kernel<<<dim3((72 + 63) / 64, Mq / 64), 256, 0, stream>>>(
        query, W_attn, b_attn, logit, Mq, 72, CDIM);
    // 4) reference points
    ref_kernel<<<B_SZ, 256, 0, stream>>>(rp, refp);
    // 5) softmax + deformable sampling
    sample_kernel<<<Mq, 384, 0, stream>>>(val, offb, logit, refp, mid);
    // 6) Wt = bf16(W_out^T); out = mid @ W_out + b_out  (MFMA)
    cast_transpose_kernel<<<(CDIM * CDIM + 255) / 256, 256, 0, stream>>>(
        W_out, Wt, CDIM, CDIM);
    gemm_mfma_kernel<<<dim3(CDIM / 128, Mq / 128), 256, 0, stream>>>(
        mid, Wt, b_out, out, Mq, CDIM, CDIM);
}

// Round 3
// 435.589 us; speedup vs baseline: 2.4772x; 1.2815x over previous
//
#include <hip/hip_runtime.h>
#include <cmath>

// Problem constants
#define B_SZ   32
#define LQ     576
#define LV     3024
#define CDIM   384
#define NHEAD  6
#define DHEAD  64
#define NLVL   3
#define NPTS   4
#define NPROJ  216   // 144 offset channels + 72 attn logits

typedef short  bx4 __attribute__((ext_vector_type(4)));
typedef short  bx8 __attribute__((ext_vector_type(8)));
typedef float  fx4 __attribute__((ext_vector_type(4)));

__device__ __forceinline__ short f2bf(float f) {
    unsigned u = __builtin_bit_cast(unsigned, f);
    unsigned r = (u + 0x7FFFu + ((u >> 16) & 1u)) >> 16;  // RNE
    return (short)r;
}
__device__ __forceinline__ float bf2f(unsigned short u) {
    return __builtin_bit_cast(float, ((unsigned)u) << 16);
}

// ---------------------------------------------------------------------------
// W (K x N fp32) -> Wt (N x K bf16)   [384x384]
// ---------------------------------------------------------------------------
__global__ __launch_bounds__(256) void cast_transpose_kernel(
    const float* __restrict__ W, short* __restrict__ Wt, int K, int N)
{
    int idx = blockIdx.x * 256 + threadIdx.x;
    if (idx >= K * N) return;
    int n = idx / K, k = idx - n * K;
    Wt[idx] = f2bf(W[(size_t)k * N + n]);
}

// ---------------------------------------------------------------------------
// Build split-bf16 transposed concat weight for the off+attn projection:
//   Wc[:,0:144]=W_off, Wc[:,144:216]=W_attn;  Wh/Wl: (216 x 384) bf16 hi/lo.
//   bc[216] = concat(b_off, b_attn).
// ---------------------------------------------------------------------------
__global__ __launch_bounds__(256) void prep_proj_kernel(
    const float* __restrict__ W_off, const float* __restrict__ b_off,
    const float* __restrict__ W_attn, const float* __restrict__ b_attn,
    short* __restrict__ Wh, short* __restrict__ Wl, float* __restrict__ bc)
{
    int idx = blockIdx.x * 256 + threadIdx.x;
    if (idx >= NPROJ * CDIM) return;
    int n = idx / CDIM, k = idx - n * CDIM;
    float w = (n < 144) ? W_off[(size_t)k * 144 + n]
                        : W_attn[(size_t)k * 72 + (n - 144)];
    short h = f2bf(w);
    float hf = bf2f((unsigned short)h);
    Wh[idx] = h;
    Wl[idx] = f2bf(w - hf);
    if (idx < NPROJ) bc[idx] = (idx < 144) ? b_off[idx] : b_attn[idx - 144];
}

// ---------------------------------------------------------------------------
// bf16 MFMA GEMM, A fp32 (cast in-flight): C = A @ Wt^T + bias
// 128x128 tile, BK=64, 256 threads. M%128==0, N%128==0, K%64==0.
// BF16_OUT selects fp32 or bf16 C.
// ---------------------------------------------------------------------------
template <bool BF16_OUT>
__global__ __launch_bounds__(256) void gemm_mfma_kernel(
    const float* __restrict__ A, const short* __restrict__ Wt,
    const float* __restrict__ bias, void* __restrict__ Cout,
    int M, int N, int K)
{
    __shared__ short As[128 * 72];
    __shared__ short Bs[128 * 72];

    const int tid = threadIdx.x;
    const int m0 = blockIdx.y * 128;
    const int n0 = blockIdx.x * 128;

    const int akq = (tid & 15) << 2;   // k offset (floats)
    const int am  = tid >> 4;          // row 0..15
    const int bk8 = (tid & 7) << 3;    // k offset (shorts)
    const int bn  = tid >> 3;          // row 0..31

    const int w  = tid >> 6;
    const int l  = tid & 63;
    const int mw = (w & 1) * 64;
    const int nw = (w >> 1) * 64;
    const int lr = l & 15;
    const int ko = (l >> 4) * 8;

    fx4 acc[4][4] = {};

    for (int k0 = 0; k0 < K; k0 += 64) {
        #pragma unroll
        for (int r = 0; r < 8; ++r) {
            const int m = am + r * 16;
            const float4 v = *(const float4*)(A + (size_t)(m0 + m) * K + k0 + akq);
            bx4 s;
            s[0] = f2bf(v.x); s[1] = f2bf(v.y); s[2] = f2bf(v.z); s[3] = f2bf(v.w);
            *(bx4*)&As[m * 72 + akq] = s;
        }
        #pragma unroll
        for (int r = 0; r < 4; ++r) {
            const int n = bn + r * 32;
            const bx8 wv = *(const bx8*)(Wt + (size_t)(n0 + n) * K + k0 + bk8);
            *(bx8*)&Bs[n * 72 + bk8] = wv;
        }
        __syncthreads();

        #pragma unroll
        for (int ks = 0; ks < 2; ++ks) {
            bx8 af[4], bfr[4];
            #pragma unroll
            for (int i = 0; i < 4; ++i)
                af[i] = *(const bx8*)&As[(mw + i * 16 + lr) * 72 + ks * 32 + ko];
            #pragma unroll
            for (int j = 0; j < 4; ++j)
                bfr[j] = *(const bx8*)&Bs[(nw + j * 16 + lr) * 72 + ks * 32 + ko];
            #pragma unroll
            for (int i = 0; i < 4; ++i)
                #pragma unroll
                for (int j = 0; j < 4; ++j)
                    acc[i][j] = __builtin_amdgcn_mfma_f32_16x16x32_bf16(
                        af[i], bfr[j], acc[i][j], 0, 0, 0);
        }
        __syncthreads();
    }

    const int rrow = (l >> 4) * 4;
    #pragma unroll
    for (int j = 0; j < 4; ++j) {
        const int col = n0 + nw + j * 16 + lr;
        const float bv = bias[col];
        #pragma unroll
        for (int i = 0; i < 4; ++i) {
            const int row = m0 + mw + i * 16 + rrow;
            #pragma unroll
            for (int r = 0; r < 4; ++r) {
                if (BF16_OUT)
                    ((short*)Cout)[(size_t)(row + r) * N + col] = f2bf(acc[i][j][r] + bv);
                else
                    ((float*)Cout)[(size_t)(row + r) * N + col] = acc[i][j][r] + bv;
            }
        }
    }
}

// ---------------------------------------------------------------------------
// bf16 MFMA GEMM, A already bf16: C(fp32) = A @ Wt^T + bias. Same tiling.
// ---------------------------------------------------------------------------
__global__ __launch_bounds__(256) void gemm_mfma_bf16A_kernel(
    const short* __restrict__ A, const short* __restrict__ Wt,
    const float* __restrict__ bias, float* __restrict__ C,
    int M, int N, int K)
{
    __shared__ short As[128 * 72];
    __shared__ short Bs[128 * 72];

    const int tid = threadIdx.x;
    const int m0 = blockIdx.y * 128;
    const int n0 = blockIdx.x * 128;

    const int k8 = (tid & 7) << 3;
    const int rr = tid >> 3;   // 0..31

    const int w  = tid >> 6;
    const int l  = tid & 63;
    const int mw = (w & 1) * 64;
    const int nw = (w >> 1) * 64;
    const int lr = l & 15;
    const int ko = (l >> 4) * 8;

    fx4 acc[4][4] = {};

    for (int k0 = 0; k0 < K; k0 += 64) {
        #pragma unroll
        for (int r = 0; r < 4; ++r) {
            const int m = rr + r * 32;
            *(bx8*)&As[m * 72 + k8] = *(const bx8*)(A + (size_t)(m0 + m) * K + k0 + k8);
            *(bx8*)&Bs[m * 72 + k8] = *(const bx8*)(Wt + (size_t)(n0 + m) * K + k0 + k8);
        }
        __syncthreads();

        #pragma unroll
        for (int ks = 0; ks < 2; ++ks) {
            bx8 af[4], bfr[4];
            #pragma unroll
            for (int i = 0; i < 4; ++i)
                af[i] = *(const bx8*)&As[(mw + i * 16 + lr) * 72 + ks * 32 + ko];
            #pragma unroll
            for (int j = 0; j < 4; ++j)
                bfr[j] = *(const bx8*)&Bs[(nw + j * 16 + lr) * 72 + ks * 32 + ko];
            #pragma unroll
            for (int i = 0; i < 4; ++i)
                #pragma unroll
                for (int j = 0; j < 4; ++j)
                    acc[i][j] = __builtin_amdgcn_mfma_f32_16x16x32_bf16(
                        af[i], bfr[j], acc[i][j], 0, 0, 0);
        }
        __syncthreads();
    }

    const int rrow = (l >> 4) * 4;
    #pragma unroll
    for (int j = 0; j < 4; ++j) {
        const int col = n0 + nw + j * 16 + lr;
        const float bv = bias[col];
        #pragma unroll
        for (int i = 0; i < 4; ++i) {
            const int row = m0 + mw + i * 16 + rrow;
            #pragma unroll
            for (int r = 0; r < 4; ++r)
                C[(size_t)(row + r) * N + col] = acc[i][j][r] + bv;
        }
    }
}

// ---------------------------------------------------------------------------
// Split-bf16 MFMA GEMM for the query projections (fp32-grade accuracy):
//   proj = query @ [W_off|W_attn] + bias.  A=Ah+Al, B=Bh+Bl,
//   acc += Ah*Bh + Ah*Bl + Al*Bh  (Al*Bl ~2^-32, dropped).
// 128x128 tile, BK=32, 256 threads. M%128==0, K%32==0; N=216 guarded.
// ---------------------------------------------------------------------------
__global__ __launch_bounds__(256) void gemm_proj_split_kernel(
    const float* __restrict__ A, const short* __restrict__ Wh,
    const short* __restrict__ Wl, const float* __restrict__ bias,
    float* __restrict__ C, int M, int N, int K)
{
    __shared__ short Ah[128 * 40];
    __shared__ short Al[128 * 40];
    __shared__ short Bh[128 * 40];
    __shared__ short Bl[128 * 40];

    const int tid = threadIdx.x;
    const int m0 = blockIdx.y * 128;
    const int n0 = blockIdx.x * 128;

    const int kq = (tid & 7) << 2;   // k offset (floats / x4 shorts)
    const int rw = tid >> 3;         // row 0..31

    const int w  = tid >> 6;
    const int l  = tid & 63;
    const int mw = (w & 1) * 64;
    const int nw = (w >> 1) * 64;
    const int lr = l & 15;
    const int ko = (l >> 4) * 8;

    fx4 acc[4][4] = {};

    for (int k0 = 0; k0 < K; k0 += 32) {
        #pragma unroll
        for (int r = 0; r < 4; ++r) {
            const int m = rw + r * 32;
            const float4 v = *(const float4*)(A + (size_t)(m0 + m) * K + k0 + kq);
            bx4 sh, sl;
            #pragma unroll
            for (int t = 0; t < 4; ++t) {
                const float f = ((const float*)&v)[t];
                const short h = f2bf(f);
                sh[t] = h;
                sl[t] = f2bf(f - bf2f((unsigned short)h));
            }
            *(bx4*)&Ah[m * 40 + kq] = sh;
            *(bx4*)&Al[m * 40 + kq] = sl;

            bx4 wh = {}, wl = {};
            if (n0 + m < N) {
                wh = *(const bx4*)(Wh + (size_t)(n0 + m) * K + k0 + kq);
                wl = *(const bx4*)(Wl + (size_t)(n0 + m) * K + k0 + kq);
            }
            *(bx4*)&Bh[m * 40 + kq] = wh;
            *(bx4*)&Bl[m * 40 + kq] = wl;
        }
        __syncthreads();

        bx8 ah[4], al[4], bh[4], bl[4];
        #pragma unroll
        for (int i = 0; i < 4; ++i) {
            ah[i] = *(const bx8*)&Ah[(mw + i * 16 + lr) * 40 + ko];
            al[i] = *(const bx8*)&Al[(mw + i * 16 + lr) * 40 + ko];
        }
        #pragma unroll
        for (int j = 0; j < 4; ++j) {
            bh[j] = *(const bx8*)&Bh[(nw + j * 16 + lr) * 40 + ko];
            bl[j] = *(const bx8*)&Bl[(nw + j * 16 + lr) * 40 + ko];
        }
        #pragma unroll
        for (int i = 0; i < 4; ++i)
            #pragma unroll
            for (int j = 0; j < 4; ++j) {
                acc[i][j] = __builtin_amdgcn_mfma_f32_16x16x32_bf16(al[i], bh[j], acc[i][j], 0, 0, 0);
                acc[i][j] = __builtin_amdgcn_mfma_f32_16x16x32_bf16(ah[i], bl[j], acc[i][j], 0, 0, 0);
                acc[i][j] = __builtin_amdgcn_mfma_f32_16x16x32_bf16(ah[i], bh[j], acc[i][j], 0, 0, 0);
            }
        __syncthreads();
    }

    const int rrow = (l >> 4) * 4;
    #pragma unroll
    for (int j = 0; j < 4; ++j) {
        const int col = n0 + nw + j * 16 + lr;
        if (col >= N) continue;
        const float bv = bias[col];
        #pragma unroll
        for (int i = 0; i < 4; ++i) {
            const int row = m0 + mw + i * 16 + rrow;
            #pragma unroll
            for (int r = 0; r < 4; ++r)
                C[(size_t)(row + r) * N + col] = acc[i][j][r] + bv;
        }
    }
}

// ---------------------------------------------------------------------------
// Reference-point processing (verified round 1)
// ---------------------------------------------------------------------------
__global__ __launch_bounds__(256) void ref_kernel(
    const float* __restrict__ rp, float* __restrict__ refp)
{
    const int b = blockIdx.x;
    const float* r = rp + (size_t)b * LV * 2;
    const int tid = threadIdx.x;

    __shared__ float redx[256], redy[256];
    float sx = 0.f, sy = 0.f;
    for (int i = tid; i < 2304; i += 256) {
        sx += r[2 * i + 0];
        sy += r[2 * i + 1];
    }
    redx[tid] = sx; redy[tid] = sy;
    __syncthreads();
    for (int s = 128; s > 0; s >>= 1) {
        if (tid < s) { redx[tid] += redx[tid + s]; redy[tid] += redy[tid + s]; }
        __syncthreads();
    }
    const float p1x = redx[0] * (1.f / 2304.f);
    const float p1y = redy[0] * (1.f / 2304.f);

    const float* g = r + 2880 * 2;
    for (int q = tid; q < 576; q += 256) {
        const float p2x = r[(2304 + q) * 2 + 0];
        const float p2y = r[(2304 + q) * 2 + 1];
        const int qy = q / 24, qx = q % 24;
        const float syc = fminf(fmaxf(0.5f * qy - 0.25f, 0.f), 11.f);
        const float sxc = fminf(fmaxf(0.5f * qx - 0.25f, 0.f), 11.f);
        int y0 = min((int)syc, 10);
        int x0 = min((int)sxc, 10);
        const float fy = syc - (float)y0, fx = sxc - (float)x0;
        const float v00x = g[(y0 * 12 + x0) * 2 + 0],     v00y = g[(y0 * 12 + x0) * 2 + 1];
        const float v10x = g[(y0 * 12 + x0 + 1) * 2 + 0], v10y = g[(y0 * 12 + x0 + 1) * 2 + 1];
        const float v01x = g[((y0 + 1) * 12 + x0) * 2 + 0],     v01y = g[((y0 + 1) * 12 + x0) * 2 + 1];
        const float v11x = g[((y0 + 1) * 12 + x0 + 1) * 2 + 0], v11y = g[((y0 + 1) * 12 + x0 + 1) * 2 + 1];
        const float p3x = (1.f - fy) * ((1.f - fx) * v00x + fx * v10x)
                        + fy * ((1.f - fx) * v01x + fx * v11x);
        const float p3y = (1.f - fy) * ((1.f - fx) * v00y + fx * v10y)
                        + fy * ((1.f - fx) * v01y + fx * v11y);
        refp[((size_t)b * LQ + q) * 2 + 0] = (p1x + p2x + p3x) * (1.f / 3.f);
        refp[((size_t)b * LQ + q) * 2 + 1] = (p1y + p2y + p3y) * (1.f / 3.f);
    }
}

// ---------------------------------------------------------------------------
// Deformable sampling + softmax + attention accumulate.
// val bf16 (B,3024,384); proj fp32 (B*576, 216) = [off 144 | logits 72];
// mid bf16 (B*576, 384). XCD-swizzled block order: each XCD group streams
// through 4 consecutive batches so the 2.3 MB/batch bf16 val slice stays
// L2-resident.
// ---------------------------------------------------------------------------
__global__ __launch_bounds__(384) void sample_kernel(
    const unsigned short* __restrict__ val, const float* __restrict__ proj,
    const float* __restrict__ refp, short* __restrict__ mid)
{
    const int i = blockIdx.x;
    const int g = i & 7;           // XCD group (heuristic blockIdx % 8)
    const int r = i >> 3;          // 0..2303
    const int b = g * 4 + (r / LQ);
    const int q = r - (r / LQ) * LQ;
    const int bq = b * LQ + q;
    const int tid = threadIdx.x;

    __shared__ float attn[72];
    __shared__ int   sloc[72][4];
    __shared__ float swt[72][4];

    if (tid < 72) {
        attn[tid] = proj[(size_t)bq * NPROJ + 144 + tid];

        const int h = tid / 12;
        const int rr = tid % 12;
        const int l = rr >> 2;
        const int p = rr & 3;

        const int HL[3] = {48, 24, 12};
        const int ST[3] = {0, 2304, 2880};
        const int Hl = HL[l], Wl = HL[l], st = ST[l];

        const float rx = refp[bq * 2 + 0];
        const float ry = refp[bq * 2 + 1];
        const int oc = ((h * NLVL + l) * NPTS + p) * 2;
        const float cx = proj[(size_t)bq * NPROJ + oc + 0] + rx;
        const float cy = proj[(size_t)bq * NPROJ + oc + 1] + ry;

        const float px = cx * (float)Wl - 0.5f;
        const float py = cy * (float)Hl - 0.5f;
        const float x0f = floorf(px), y0f = floorf(py);
        const float lx = px - x0f, ly = py - y0f;
        const int x0 = (int)x0f, y0 = (int)y0f;

        #pragma unroll
        for (int k = 0; k < 4; ++k) {
            const int dx = k & 1, dy = k >> 1;
            const int xi = x0 + dx, yi = y0 + dy;
            const bool v = (xi >= 0) && (xi < Wl) && (yi >= 0) && (yi < Hl);
            const int xc = min(max(xi, 0), Wl - 1);
            const int yc = min(max(yi, 0), Hl - 1);
            sloc[tid][k] = st + yc * Wl + xc;
            const float wx = dx ? lx : 1.f - lx;
            const float wy = dy ? ly : 1.f - ly;
            swt[tid][k] = v ? wx * wy : 0.f;
        }
    }
    __syncthreads();

    if (tid < NHEAD) {
        float mx = -1e30f;
        #pragma unroll
        for (int j = 0; j < 12; ++j) mx = fmaxf(mx, attn[tid * 12 + j]);
        float s = 0.f;
        #pragma unroll
        for (int j = 0; j < 12; ++j) {
            const float e = expf(attn[tid * 12 + j] - mx);
            attn[tid * 12 + j] = e;
            s += e;
        }
        const float inv = 1.f / s;
        #pragma unroll
        for (int j = 0; j < 12; ++j) attn[tid * 12 + j] *= inv;
    }
    __syncthreads();

    const int h = tid >> 6;
    const int c = tid & 63;
    const unsigned short* vb = val + (size_t)b * LV * CDIM + h * DHEAD + c;
    float acc = 0.f;
    #pragma unroll
    for (int s = 0; s < 12; ++s) {
        const int j = h * 12 + s;
        const float a = attn[j];
        const float sum = swt[j][0] * bf2f(vb[(size_t)sloc[j][0] * CDIM])
                        + swt[j][1] * bf2f(vb[(size_t)sloc[j][1] * CDIM])
                        + swt[j][2] * bf2f(vb[(size_t)sloc[j][2] * CDIM])
                        + swt[j][3] * bf2f(vb[(size_t)sloc[j][3] * CDIM]);
        acc += a * sum;
    }
    mid[(size_t)bq * CDIM + tid] = f2bf(acc);
}

// ---------------------------------------------------------------------------
extern "C" void kernel_launch(void* const* d_in, const int* in_sizes, int n_in,
                              void* d_out, int out_size, void* d_ws, size_t ws_size,
                              hipStream_t stream)
{
    (void)in_sizes; (void)n_in; (void)out_size; (void)ws_size;

    const float* query   = (const float*)d_in[0];
    const float* value   = (const float*)d_in[1];
    const float* rp      = (const float*)d_in[2];
    const float* W_value = (const float*)d_in[3];
    const float* b_value = (const float*)d_in[4];
    const float* W_off   = (const float*)d_in[5];
    const float* b_off   = (const float*)d_in[6];
    const float* W_attn  = (const float*)d_in[7];
    const float* b_attn  = (const float*)d_in[8];
    const float* W_out   = (const float*)d_in[9];
    const float* b_out   = (const float*)d_in[10];
    float* out = (float*)d_out;

    // Workspace layout (256-B aligned chunks)
    char* p = (char*)d_ws;
    auto take = [&](size_t bytes) { char* q = p; p += (bytes + 255) & ~(size_t)255; return q; };
    short* val  = (short*)take((size_t)B_SZ * LV * CDIM * 2);     // bf16 val
    short* mid  = (short*)take((size_t)B_SZ * LQ * CDIM * 2);     // bf16 mid
    short* Wt   = (short*)take((size_t)CDIM * CDIM * 2);          // bf16 W^T (reused)
    short* Wh   = (short*)take((size_t)NPROJ * CDIM * 2);
    short* Wl   = (short*)take((size_t)NPROJ * CDIM * 2);
    float* proj = (float*)take((size_t)B_SZ * LQ * NPROJ * 4);
    float* refp = (float*)take((size_t)B_SZ * LQ * 2 * 4);
    float* bc   = (float*)take((size_t)NPROJ * 4);

    const int Mv = B_SZ * LV;   // 96768
    const int Mq = B_SZ * LQ;   // 18432

    // 1) val = bf16(value @ W_value + b_value)   (MFMA, bf16 out)
    cast_transpose_kernel<<<(CDIM * CDIM + 255) / 256, 256, 0, stream>>>(
        W_value, Wt, CDIM, CDIM);
    gemm_mfma_kernel<true><<<dim3(CDIM / 128, Mv / 128), 256, 0, stream>>>(
        value, Wt, b_value, val, Mv, CDIM, CDIM);
    // 2) proj = query @ [W_off|W_attn] + bias    (split-bf16 MFMA, fp32-grade)
    prep_proj_kernel<<<(NPROJ * CDIM + 255) / 256, 256, 0, stream>>>(
        W_off, b_off, W_attn, b_attn, Wh, Wl, bc);
    gemm_proj_split_kernel<<<dim3((NPROJ + 127) / 128, Mq / 128), 256, 0, stream>>>(
        query, Wh, Wl, bc, proj, Mq, NPROJ, CDIM);
    // 3) reference points
    ref_kernel<<<B_SZ, 256, 0, stream>>>(rp, refp);
    // 4) softmax + deformable sampling (XCD-swizzled)
    sample_kernel<<<Mq, 384, 0, stream>>>(
        (const unsigned short*)val, proj, refp, mid);
    // 5) out = mid @ W_out + b_out               (MFMA, bf16 A)
    cast_transpose_kernel<<<(CDIM * CDIM + 255) / 256, 256, 0, stream>>>(
        W_out, Wt, CDIM, CDIM);
    gemm_mfma_bf16A_kernel<<<dim3(CDIM / 128, Mq / 128), 256, 0, stream>>>(
        mid, Wt, b_out, out, Mq, CDIM, CDIM);
}

// Round 4
// 425.722 us; speedup vs baseline: 2.5347x; 1.0232x over previous
//
#include <hip/hip_runtime.h>
#include <cmath>

// Problem constants
#define B_SZ   32
#define LQ     576
#define LV     3024
#define CDIM   384
#define NHEAD  6
#define DHEAD  64
#define NLVL   3
#define NPTS   4
#define NPROJ  216   // 144 offset channels + 72 attn logits

typedef short  bx4 __attribute__((ext_vector_type(4)));
typedef short  bx8 __attribute__((ext_vector_type(8)));
typedef float  fx4 __attribute__((ext_vector_type(4)));

__device__ __forceinline__ short f2bf(float f) {
    unsigned u = __builtin_bit_cast(unsigned, f);
    unsigned r = (u + 0x7FFFu + ((u >> 16) & 1u)) >> 16;  // RNE
    return (short)r;
}
__device__ __forceinline__ float bf2f(unsigned short u) {
    return __builtin_bit_cast(float, ((unsigned)u) << 16);
}

// ---------------------------------------------------------------------------
// W (K x N fp32) -> Wt (N x K bf16)   [384x384]
// ---------------------------------------------------------------------------
__global__ __launch_bounds__(256) void cast_transpose_kernel(
    const float* __restrict__ W, short* __restrict__ Wt, int K, int N)
{
    int idx = blockIdx.x * 256 + threadIdx.x;
    if (idx >= K * N) return;
    int n = idx / K, k = idx - n * K;
    Wt[idx] = f2bf(W[(size_t)k * N + n]);
}

// ---------------------------------------------------------------------------
// Split-bf16 concat weight for off+attn projection (fp32-grade path).
// ---------------------------------------------------------------------------
__global__ __launch_bounds__(256) void prep_proj_kernel(
    const float* __restrict__ W_off, const float* __restrict__ b_off,
    const float* __restrict__ W_attn, const float* __restrict__ b_attn,
    short* __restrict__ Wh, short* __restrict__ Wl, float* __restrict__ bc)
{
    int idx = blockIdx.x * 256 + threadIdx.x;
    if (idx >= NPROJ * CDIM) return;
    int n = idx / CDIM, k = idx - n * CDIM;
    float w = (n < 144) ? W_off[(size_t)k * 144 + n]
                        : W_attn[(size_t)k * 72 + (n - 144)];
    short h = f2bf(w);
    float hf = bf2f((unsigned short)h);
    Wh[idx] = h;
    Wl[idx] = f2bf(w - hf);
    if (idx < NPROJ) bc[idx] = (idx < 144) ? b_off[idx] : b_attn[idx - 144];
}

// ---------------------------------------------------------------------------
// Full-N bf16 MFMA GEMM: C[M,384] = A[M,K] @ Wt[384,K]^T + bias.
// One block = 128 rows x ALL 384 cols -> A fetched exactly once from HBM.
// 512 threads = 8 waves; wave (w&1)=row half (64), (w>>2... w>>1)=col quarter
// (96 = 6x16). BK=64. A_FP32: cast in-flight; else bf16 passthrough.
// LDS: As 128x72 + Bs 384x72 shorts = 73.7 KB.
// ---------------------------------------------------------------------------
template <bool A_FP32, bool OUT_BF16>
__global__ __launch_bounds__(512) void gemm_fullN_kernel(
    const void* __restrict__ Av, const short* __restrict__ Wt,
    const float* __restrict__ bias, void* __restrict__ Cout,
    int M, int K)
{
    constexpr int N = 384;
    __shared__ short As[128 * 72];
    __shared__ short Bs[384 * 72];

    const int tid = threadIdx.x;
    const int m0 = blockIdx.x * 128;

    const int w  = tid >> 6;           // wave 0..7
    const int l  = tid & 63;
    const int wr = (w & 1) * 64;       // row offset within tile
    const int wc = (w >> 1) * 96;      // col offset (6 x 16)
    const int lr = l & 15;
    const int ko = (l >> 4) * 8;

    fx4 acc[4][6] = {};

    for (int k0 = 0; k0 < K; k0 += 64) {
        if (A_FP32) {
            const float* A = (const float*)Av;
            #pragma unroll
            for (int r = 0; r < 4; ++r) {          // 128 rows x 16 float4 chunks
                const int id = tid + r * 512;
                const int m  = id >> 4;
                const int kq = (id & 15) << 2;
                const float4 v = *(const float4*)(A + (size_t)(m0 + m) * K + k0 + kq);
                bx4 s;
                s[0] = f2bf(v.x); s[1] = f2bf(v.y); s[2] = f2bf(v.z); s[3] = f2bf(v.w);
                *(bx4*)&As[m * 72 + kq] = s;
            }
        } else {
            const short* A = (const short*)Av;
            #pragma unroll
            for (int r = 0; r < 2; ++r) {          // 128 rows x 8 short8 chunks
                const int id = tid + r * 512;
                const int m  = id >> 3;
                const int k8 = (id & 7) << 3;
                *(bx8*)&As[m * 72 + k8] = *(const bx8*)(A + (size_t)(m0 + m) * K + k0 + k8);
            }
        }
        #pragma unroll
        for (int r = 0; r < 6; ++r) {              // 384 rows x 8 short8 chunks
            const int id = tid + r * 512;
            const int n  = id >> 3;
            const int k8 = (id & 7) << 3;
            *(bx8*)&Bs[n * 72 + k8] = *(const bx8*)(Wt + (size_t)n * K + k0 + k8);
        }
        __syncthreads();

        #pragma unroll
        for (int ks = 0; ks < 2; ++ks) {
            bx8 af[4], bfr[6];
            #pragma unroll
            for (int i = 0; i < 4; ++i)
                af[i] = *(const bx8*)&As[(wr + i * 16 + lr) * 72 + ks * 32 + ko];
            #pragma unroll
            for (int j = 0; j < 6; ++j)
                bfr[j] = *(const bx8*)&Bs[(wc + j * 16 + lr) * 72 + ks * 32 + ko];
            #pragma unroll
            for (int i = 0; i < 4; ++i)
                #pragma unroll
                for (int j = 0; j < 6; ++j)
                    acc[i][j] = __builtin_amdgcn_mfma_f32_16x16x32_bf16(
                        af[i], bfr[j], acc[i][j], 0, 0, 0);
        }
        __syncthreads();
    }

    // Epilogue: C/D layout col=lane&15, row=(lane>>4)*4+reg
    const int rrow = (l >> 4) * 4;
    #pragma unroll
    for (int j = 0; j < 6; ++j) {
        const int col = wc + j * 16 + lr;
        const float bv = bias[col];
        #pragma unroll
        for (int i = 0; i < 4; ++i) {
            const int row = m0 + wr + i * 16 + rrow;
            #pragma unroll
            for (int r = 0; r < 4; ++r) {
                if (OUT_BF16)
                    ((short*)Cout)[(size_t)(row + r) * N + col] = f2bf(acc[i][j][r] + bv);
                else
                    ((float*)Cout)[(size_t)(row + r) * N + col] = acc[i][j][r] + bv;
            }
        }
    }
}

// ---------------------------------------------------------------------------
// Split-bf16 MFMA GEMM for query projections (fp32-grade):
//   acc += Ah*Bh + Ah*Bl + Al*Bh.  128x128 tile, BK=32, 256 threads.
// ---------------------------------------------------------------------------
__global__ __launch_bounds__(256) void gemm_proj_split_kernel(
    const float* __restrict__ A, const short* __restrict__ Wh,
    const short* __restrict__ Wl, const float* __restrict__ bias,
    float* __restrict__ C, int M, int N, int K)
{
    __shared__ short Ah[128 * 40];
    __shared__ short Al[128 * 40];
    __shared__ short Bh[128 * 40];
    __shared__ short Bl[128 * 40];

    const int tid = threadIdx.x;
    const int m0 = blockIdx.y * 128;
    const int n0 = blockIdx.x * 128;

    const int kq = (tid & 7) << 2;
    const int rw = tid >> 3;

    const int w  = tid >> 6;
    const int l  = tid & 63;
    const int mw = (w & 1) * 64;
    const int nw = (w >> 1) * 64;
    const int lr = l & 15;
    const int ko = (l >> 4) * 8;

    fx4 acc[4][4] = {};

    for (int k0 = 0; k0 < K; k0 += 32) {
        #pragma unroll
        for (int r = 0; r < 4; ++r) {
            const int m = rw + r * 32;
            const float4 v = *(const float4*)(A + (size_t)(m0 + m) * K + k0 + kq);
            bx4 sh, sl;
            #pragma unroll
            for (int t = 0; t < 4; ++t) {
                const float f = ((const float*)&v)[t];
                const short h = f2bf(f);
                sh[t] = h;
                sl[t] = f2bf(f - bf2f((unsigned short)h));
            }
            *(bx4*)&Ah[m * 40 + kq] = sh;
            *(bx4*)&Al[m * 40 + kq] = sl;

            bx4 wh = {}, wl = {};
            if (n0 + m < N) {
                wh = *(const bx4*)(Wh + (size_t)(n0 + m) * K + k0 + kq);
                wl = *(const bx4*)(Wl + (size_t)(n0 + m) * K + k0 + kq);
            }
            *(bx4*)&Bh[m * 40 + kq] = wh;
            *(bx4*)&Bl[m * 40 + kq] = wl;
        }
        __syncthreads();

        bx8 ah[4], al[4], bh[4], bl[4];
        #pragma unroll
        for (int i = 0; i < 4; ++i) {
            ah[i] = *(const bx8*)&Ah[(mw + i * 16 + lr) * 40 + ko];
            al[i] = *(const bx8*)&Al[(mw + i * 16 + lr) * 40 + ko];
        }
        #pragma unroll
        for (int j = 0; j < 4; ++j) {
            bh[j] = *(const bx8*)&Bh[(nw + j * 16 + lr) * 40 + ko];
            bl[j] = *(const bx8*)&Bl[(nw + j * 16 + lr) * 40 + ko];
        }
        #pragma unroll
        for (int i = 0; i < 4; ++i)
            #pragma unroll
            for (int j = 0; j < 4; ++j) {
                acc[i][j] = __builtin_amdgcn_mfma_f32_16x16x32_bf16(al[i], bh[j], acc[i][j], 0, 0, 0);
                acc[i][j] = __builtin_amdgcn_mfma_f32_16x16x32_bf16(ah[i], bl[j], acc[i][j], 0, 0, 0);
                acc[i][j] = __builtin_amdgcn_mfma_f32_16x16x32_bf16(ah[i], bh[j], acc[i][j], 0, 0, 0);
            }
        __syncthreads();
    }

    const int rrow = (l >> 4) * 4;
    #pragma unroll
    for (int j = 0; j < 4; ++j) {
        const int col = n0 + nw + j * 16 + lr;
        if (col >= N) continue;
        const float bv = bias[col];
        #pragma unroll
        for (int i = 0; i < 4; ++i) {
            const int row = m0 + mw + i * 16 + rrow;
            #pragma unroll
            for (int r = 0; r < 4; ++r)
                C[(size_t)(row + r) * N + col] = acc[i][j][r] + bv;
        }
    }
}

// ---------------------------------------------------------------------------
// Reference-point processing (verified round 1)
// ---------------------------------------------------------------------------
__global__ __launch_bounds__(256) void ref_kernel(
    const float* __restrict__ rp, float* __restrict__ refp)
{
    const int b = blockIdx.x;
    const float* r = rp + (size_t)b * LV * 2;
    const int tid = threadIdx.x;

    __shared__ float redx[256], redy[256];
    float sx = 0.f, sy = 0.f;
    for (int i = tid; i < 2304; i += 256) {
        sx += r[2 * i + 0];
        sy += r[2 * i + 1];
    }
    redx[tid] = sx; redy[tid] = sy;
    __syncthreads();
    for (int s = 128; s > 0; s >>= 1) {
        if (tid < s) { redx[tid] += redx[tid + s]; redy[tid] += redy[tid + s]; }
        __syncthreads();
    }
    const float p1x = redx[0] * (1.f / 2304.f);
    const float p1y = redy[0] * (1.f / 2304.f);

    const float* g = r + 2880 * 2;
    for (int q = tid; q < 576; q += 256) {
        const float p2x = r[(2304 + q) * 2 + 0];
        const float p2y = r[(2304 + q) * 2 + 1];
        const int qy = q / 24, qx = q % 24;
        const float syc = fminf(fmaxf(0.5f * qy - 0.25f, 0.f), 11.f);
        const float sxc = fminf(fmaxf(0.5f * qx - 0.25f, 0.f), 11.f);
        int y0 = min((int)syc, 10);
        int x0 = min((int)sxc, 10);
        const float fy = syc - (float)y0, fx = sxc - (float)x0;
        const float v00x = g[(y0 * 12 + x0) * 2 + 0],     v00y = g[(y0 * 12 + x0) * 2 + 1];
        const float v10x = g[(y0 * 12 + x0 + 1) * 2 + 0], v10y = g[(y0 * 12 + x0 + 1) * 2 + 1];
        const float v01x = g[((y0 + 1) * 12 + x0) * 2 + 0],     v01y = g[((y0 + 1) * 12 + x0) * 2 + 1];
        const float v11x = g[((y0 + 1) * 12 + x0 + 1) * 2 + 0], v11y = g[((y0 + 1) * 12 + x0 + 1) * 2 + 1];
        const float p3x = (1.f - fy) * ((1.f - fx) * v00x + fx * v10x)
                        + fy * ((1.f - fx) * v01x + fx * v11x);
        const float p3y = (1.f - fy) * ((1.f - fx) * v00y + fx * v10y)
                        + fy * ((1.f - fx) * v01y + fx * v11y);
        refp[((size_t)b * LQ + q) * 2 + 0] = (p1x + p2x + p3x) * (1.f / 3.f);
        refp[((size_t)b * LQ + q) * 2 + 1] = (p1y + p2y + p3y) * (1.f / 3.f);
    }
}

// ---------------------------------------------------------------------------
// Deformable sampling + softmax + attention accumulate (verified round 3).
// ---------------------------------------------------------------------------
__global__ __launch_bounds__(384) void sample_kernel(
    const unsigned short* __restrict__ val, const float* __restrict__ proj,
    const float* __restrict__ refp, short* __restrict__ mid)
{
    const int i = blockIdx.x;
    const int g = i & 7;           // XCD group swizzle
    const int r = i >> 3;
    const int b = g * 4 + (r / LQ);
    const int q = r - (r / LQ) * LQ;
    const int bq = b * LQ + q;
    const int tid = threadIdx.x;

    __shared__ float attn[72];
    __shared__ int   sloc[72][4];
    __shared__ float swt[72][4];

    if (tid < 72) {
        attn[tid] = proj[(size_t)bq * NPROJ + 144 + tid];

        const int h = tid / 12;
        const int rr = tid % 12;
        const int l = rr >> 2;
        const int p = rr & 3;

        const int HL[3] = {48, 24, 12};
        const int ST[3] = {0, 2304, 2880};
        const int Hl = HL[l], Wl = HL[l], st = ST[l];

        const float rx = refp[bq * 2 + 0];
        const float ry = refp[bq * 2 + 1];
        const int oc = ((h * NLVL + l) * NPTS + p) * 2;
        const float cx = proj[(size_t)bq * NPROJ + oc + 0] + rx;
        const float cy = proj[(size_t)bq * NPROJ + oc + 1] + ry;

        const float px = cx * (float)Wl - 0.5f;
        const float py = cy * (float)Hl - 0.5f;
        const float x0f = floorf(px), y0f = floorf(py);
        const float lx = px - x0f, ly = py - y0f;
        const int x0 = (int)x0f, y0 = (int)y0f;

        #pragma unroll
        for (int k = 0; k < 4; ++k) {
            const int dx = k & 1, dy = k >> 1;
            const int xi = x0 + dx, yi = y0 + dy;
            const bool v = (xi >= 0) && (xi < Wl) && (yi >= 0) && (yi < Hl);
            const int xc = min(max(xi, 0), Wl - 1);
            const int yc = min(max(yi, 0), Hl - 1);
            sloc[tid][k] = st + yc * Wl + xc;
            const float wx = dx ? lx : 1.f - lx;
            const float wy = dy ? ly : 1.f - ly;
            swt[tid][k] = v ? wx * wy : 0.f;
        }
    }
    __syncthreads();

    if (tid < NHEAD) {
        float mx = -1e30f;
        #pragma unroll
        for (int j = 0; j < 12; ++j) mx = fmaxf(mx, attn[tid * 12 + j]);
        float s = 0.f;
        #pragma unroll
        for (int j = 0; j < 12; ++j) {
            const float e = expf(attn[tid * 12 + j] - mx);
            attn[tid * 12 + j] = e;
            s += e;
        }
        const float inv = 1.f / s;
        #pragma unroll
        for (int j = 0; j < 12; ++j) attn[tid * 12 + j] *= inv;
    }
    __syncthreads();

    const int h = tid >> 6;
    const int c = tid & 63;
    const unsigned short* vb = val + (size_t)b * LV * CDIM + h * DHEAD + c;
    float acc = 0.f;
    #pragma unroll
    for (int s = 0; s < 12; ++s) {
        const int j = h * 12 + s;
        const float a = attn[j];
        const float sum = swt[j][0] * bf2f(vb[(size_t)sloc[j][0] * CDIM])
                        + swt[j][1] * bf2f(vb[(size_t)sloc[j][1] * CDIM])
                        + swt[j][2] * bf2f(vb[(size_t)sloc[j][2] * CDIM])
                        + swt[j][3] * bf2f(vb[(size_t)sloc[j][3] * CDIM]);
        acc += a * sum;
    }
    mid[(size_t)bq * CDIM + tid] = f2bf(acc);
}

// ---------------------------------------------------------------------------
extern "C" void kernel_launch(void* const* d_in, const int* in_sizes, int n_in,
                              void* d_out, int out_size, void* d_ws, size_t ws_size,
                              hipStream_t stream)
{
    (void)in_sizes; (void)n_in; (void)out_size; (void)ws_size;

    const float* query   = (const float*)d_in[0];
    const float* value   = (const float*)d_in[1];
    const float* rp      = (const float*)d_in[2];
    const float* W_value = (const float*)d_in[3];
    const float* b_value = (const float*)d_in[4];
    const float* W_off   = (const float*)d_in[5];
    const float* b_off   = (const float*)d_in[6];
    const float* W_attn  = (const float*)d_in[7];
    const float* b_attn  = (const float*)d_in[8];
    const float* W_out   = (const float*)d_in[9];
    const float* b_out   = (const float*)d_in[10];
    float* out = (float*)d_out;

    // Workspace layout (256-B aligned chunks)
    char* p = (char*)d_ws;
    auto take = [&](size_t bytes) { char* q = p; p += (bytes + 255) & ~(size_t)255; return q; };
    short* val  = (short*)take((size_t)B_SZ * LV * CDIM * 2);     // bf16 val
    short* mid  = (short*)take((size_t)B_SZ * LQ * CDIM * 2);     // bf16 mid
    short* Wtv  = (short*)take((size_t)CDIM * CDIM * 2);          // bf16 W_value^T
    short* Wto  = (short*)take((size_t)CDIM * CDIM * 2);          // bf16 W_out^T
    short* Wh   = (short*)take((size_t)NPROJ * CDIM * 2);
    short* Wl   = (short*)take((size_t)NPROJ * CDIM * 2);
    float* proj = (float*)take((size_t)B_SZ * LQ * NPROJ * 4);
    float* refp = (float*)take((size_t)B_SZ * LQ * 2 * 4);
    float* bc   = (float*)take((size_t)NPROJ * 4);

    const int Mv = B_SZ * LV;   // 96768
    const int Mq = B_SZ * LQ;   // 18432

    // 1) val = bf16(value @ W_value + b_value)   (full-N MFMA, A read once)
    cast_transpose_kernel<<<(CDIM * CDIM + 255) / 256, 256, 0, stream>>>(
        W_value, Wtv, CDIM, CDIM);
    gemm_fullN_kernel<true, true><<<Mv / 128, 512, 0, stream>>>(
        value, Wtv, b_value, val, Mv, CDIM);
    // 2) proj = query @ [W_off|W_attn] + bias    (split-bf16, fp32-grade)
    prep_proj_kernel<<<(NPROJ * CDIM + 255) / 256, 256, 0, stream>>>(
        W_off, b_off, W_attn, b_attn, Wh, Wl, bc);
    gemm_proj_split_kernel<<<dim3((NPROJ + 127) / 128, Mq / 128), 256, 0, stream>>>(
        query, Wh, Wl, bc, proj, Mq, NPROJ, CDIM);
    // 3) reference points
    ref_kernel<<<B_SZ, 256, 0, stream>>>(rp, refp);
    // 4) softmax + deformable sampling (XCD-swizzled)
    sample_kernel<<<Mq, 384, 0, stream>>>(
        (const unsigned short*)val, proj, refp, mid);
    // 5) out = mid @ W_out + b_out               (full-N MFMA, bf16 A)
    cast_transpose_kernel<<<(CDIM * CDIM + 255) / 256, 256, 0, stream>>>(
        W_out, Wto, CDIM, CDIM);
    gemm_fullN_kernel<false, false><<<Mq / 128, 512, 0, stream>>>(
        mid, Wto, b_out, out, Mq, CDIM);
}